// Round 7
// baseline (87.705 us; speedup 1.0000x reference)
//
#include <hip/hip_runtime.h>
#include <hip/hip_bf16.h>

typedef __attribute__((ext_vector_type(8))) short short8;
typedef __attribute__((ext_vector_type(4))) short short4v;
typedef __attribute__((ext_vector_type(4))) float f32x4;
typedef __attribute__((ext_vector_type(8))) __bf16 bf16x8;

#define BB 8
#define CC 64
#define NN 65536        // H*W = 256*256
#define SPLIT1 64       // k1 blocks per batch (512 total = 2 blocks/CU; LDS caps at 2)
#define COLS1 (NN / SPLIT1)   // 1024 cols per k1 block
#define TILE_C 128            // fp32 tile cols: 64 x 128 x 4B = 32 KB per buffer
#define NT1 (COLS1 / TILE_C)  // 8 tiles per block
#define SPLIT3 128      // k3 blocks per batch

__device__ inline short f2bf(float f) {
    __hip_bfloat16 h = __float2bfloat16(f);
    return __builtin_bit_cast(short, h);
}

// --- MFMA wrapper: tolerate either short8 or bf16x8 builtin signature ---
template <typename V>
__device__ inline auto mfma_bf16_impl(V a, V b, f32x4 c, int)
    -> decltype(__builtin_amdgcn_mfma_f32_16x16x32_bf16(a, b, c, 0, 0, 0)) {
    return __builtin_amdgcn_mfma_f32_16x16x32_bf16(a, b, c, 0, 0, 0);
}
template <typename V>
__device__ inline f32x4 mfma_bf16_impl(V a, V b, f32x4 c, long) {
    bf16x8 a2 = __builtin_bit_cast(bf16x8, a);
    bf16x8 b2 = __builtin_bit_cast(bf16x8, b);
    return __builtin_amdgcn_mfma_f32_16x16x32_bf16(a2, b2, c, 0, 0, 0);
}
__device__ inline f32x4 mfma16(short8 a, short8 b, f32x4 c) {
    return mfma_bf16_impl(a, b, c, 0);
}

// ---- async global->LDS staging of one 64x128 fp32 tile ----------------------
// LDS dest LINEAR (HW requirement); XOR swizzle ((row&31)<<4 on in-row byte
// offset) applied to the GLOBAL source address (rule #21: both-sides).
__device__ inline void stage_tile(const float* __restrict__ xb, int colbase,
                                  float* buf, int tid) {
    const int half = tid >> 5;
    const int sl   = tid & 31;
#pragma unroll
    for (int i = 0; i < 8; ++i) {
        const int row   = i * 8 + half;                  // 0..63
        const int gbyte = (sl * 16) ^ ((row & 31) << 4); // pre-swizzled source
        const float* gp = xb + (size_t)row * NN + colbase + (gbyte >> 2);
        float* lp = buf + i * 1024 + tid * 4;            // linear LDS dest
        __builtin_amdgcn_global_load_lds(
            (const __attribute__((address_space(1))) void*)gp,
            (__attribute__((address_space(3))) void*)lp, 16, 0, 0);
    }
}

// read 8 consecutive fp32 tile elements (row, cols c0..c0+7) through the swizzle
__device__ inline void lds_read8(const float* buf, int row, int c0, float* v) {
    const char* rb = (const char*)(buf + row * TILE_C);
    const int swz = (row & 31) << 4;
    const f32x4 u0 = *reinterpret_cast<const f32x4*>(rb + ((c0 * 4) ^ swz));
    const f32x4 u1 = *reinterpret_cast<const f32x4*>(rb + (((c0 * 4) + 16) ^ swz));
    v[0] = u0[0]; v[1] = u0[1]; v[2] = u0[2]; v[3] = u0[3];
    v[4] = u1[0]; v[5] = u1[1]; v[6] = u1[2]; v[7] = u1[3];
}

__device__ inline short8 cvt8(const float* v) {
    short8 r;
#pragma unroll
    for (int j = 0; j < 8; ++j) r[j] = f2bf(v[j]);
    return r;
}

// ------- Kernel 1: partial Gram (bf16 MFMA) + channel sums (+bf16 x-cache) ---
template <bool CACHE>
__global__ __launch_bounds__(256) void k1_gram(const float* __restrict__ x,
                                               float* __restrict__ partialG,
                                               float* __restrict__ partialS,
                                               unsigned short* __restrict__ xbf) {
    __shared__ float lbuf[2][CC * TILE_C];   // 2 x 32 KB
    const int blk  = blockIdx.x;
    const int b    = blk / SPLIT1;
    const int s    = blk % SPLIT1;
    const int tid  = threadIdx.x;
    const int w    = tid >> 6, lane = tid & 63, lg = lane >> 4, lr = lane & 15;
    const float* xb = x + (size_t)b * CC * NN;
    unsigned short* xbfb = xbf + (size_t)b * CC * NN;
    const int colbase0 = s * COLS1;

    f32x4 acc[4];
#pragma unroll
    for (int dt = 0; dt < 4; ++dt) acc[dt] = (f32x4){0.f, 0.f, 0.f, 0.f};
    float asum = 0.f;

    stage_tile(xb, colbase0, lbuf[0], tid);
    __syncthreads();   // compiler drains vmcnt before barrier

    for (int t = 0; t < NT1; ++t) {
        if (t + 1 < NT1)
            stage_tile(xb, colbase0 + (t + 1) * TILE_C, lbuf[(t + 1) & 1], tid);
        const int colbase = colbase0 + t * TILE_C;
        const float* buf = lbuf[t & 1];
#pragma unroll
        for (int kk = 0; kk < TILE_C / 32; ++kk) {
            const int c0 = kk * 32 + lg * 8;
            float av[8];
            lds_read8(buf, w * 16 + lr, c0, av);
#pragma unroll
            for (int j = 0; j < 8; ++j) asum += av[j];
            const short8 af = cvt8(av);
#pragma unroll
            for (int dt = 0; dt < 4; ++dt) {
                float bv[8];
                lds_read8(buf, dt * 16 + lr, c0, bv);
                const short8 bf = cvt8(bv);
                acc[dt] = mfma16(af, bf, acc[dt]);
            }
        }
        // ---- write bf16 copy of this tile (coalesced: 2 rows x 256 B/wave) ----
        if (CACHE) {
            const int half = tid >> 5, sl = tid & 31;
#pragma unroll
            for (int i = 0; i < 8; ++i) {
                const int row   = i * 8 + half;
                const int gbyte = (sl * 16) ^ ((row & 31) << 4);
                const f32x4 v = *reinterpret_cast<const f32x4*>(buf + i * 1024 + tid * 4);
                short4v sv;
                sv.x = f2bf(v[0]); sv.y = f2bf(v[1]); sv.z = f2bf(v[2]); sv.w = f2bf(v[3]);
                *reinterpret_cast<short4v*>(
                    (char*)(xbfb + (size_t)row * NN + colbase) + (gbyte >> 1)) = sv;
            }
        }
        __syncthreads();
    }
    // ---- write partial Gram (C/D map: col=lane&15, row=(lane>>4)*4+reg) ----
#pragma unroll
    for (int dt = 0; dt < 4; ++dt) {
#pragma unroll
        for (int r = 0; r < 4; ++r) {
            const int c = w * 16 + lg * 4 + r;
            const int d = dt * 16 + lr;
            partialG[(size_t)blk * 4096 + c * 64 + d] = acc[dt][r];
        }
    }
    // ---- channel sums ----
    float v = asum;
    v += __shfl_xor(v, 16);
    v += __shfl_xor(v, 32);
    if (lg == 0) partialS[blk * CC + w * 16 + lr] = v;
}

// ---------------- Kernel 2a: reduce partial Gram over splits ----------------
__global__ __launch_bounds__(256) void k2a_reduceG(const float* __restrict__ partialG,
                                                   float* __restrict__ Gsum) {
    const int gid = blockIdx.x * 256 + threadIdx.x;   // 0..32767
    const int b = gid >> 12;
    const int e = gid & 4095;
    float s = 0.f;
    for (int sp = 0; sp < SPLIT1; ++sp)
        s += partialG[(((size_t)(b * SPLIT1 + sp)) << 12) + e];
    Gsum[gid] = s;
}

// ------- Kernel 2b: means, energy, softmax -> att(bf16) + offsets -----------
__global__ __launch_bounds__(256) void k2b_softmax(const float* __restrict__ partialS,
                                                   const float* __restrict__ Gsum,
                                                   unsigned short* __restrict__ att,
                                                   float* __restrict__ offs) {
    __shared__ float mu[CC];
    __shared__ float ener[CC * CC];
    const int b = blockIdx.x;
    const int tid = threadIdx.x;
    if (tid < CC) {
        float s = 0.f;
        for (int sp = 0; sp < SPLIT1; ++sp) s += partialS[(b * SPLIT1 + sp) * CC + tid];
        mu[tid] = s * (1.f / NN);
    }
    __syncthreads();
    const float inv_n = 1.f / NN;
#pragma unroll
    for (int k = 0; k < 16; ++k) {
        const int e = tid + k * 256;
        const int c = e >> 6, d = e & 63;
        ener[e] = Gsum[(b << 12) + e] * inv_n - mu[c] * mu[d];
    }
    __syncthreads();
    const int w = tid >> 6, lane = tid & 63;
    for (int i = 0; i < 16; ++i) {
        const int c = w * 16 + i;
        const float v = ener[c * 64 + lane];
        float m = v;
        for (int off = 32; off > 0; off >>= 1) m = fmaxf(m, __shfl_xor(m, off));
        const float ev = __expf(v - m);
        float sum = ev;
        for (int off = 32; off > 0; off >>= 1) sum += __shfl_xor(sum, off);
        const float a = ev / sum;
        att[(b << 12) + c * 64 + lane] = (unsigned short)f2bf(a);
        float o = a * mu[lane];
        for (int off = 32; off > 0; off >>= 1) o += __shfl_xor(o, off);
        if (lane == 0) offs[b * CC + c] = o;
    }
}

// ---------------- Kernel 3: out = gamma * (A @ x - offset) ------------------
// CACHE: read the 67 MB bf16 copy (L3-resident) instead of 134 MB fp32 x.
// Non-temporal stores keep the cache resident in Infinity Cache.
template <bool CACHE>
__global__ __launch_bounds__(256) void k3_apply(const float* __restrict__ x,
                                                const unsigned short* __restrict__ xbf,
                                                const unsigned short* __restrict__ att,
                                                const float* __restrict__ offs,
                                                const float* __restrict__ gamma,
                                                float* __restrict__ out) {
    const int blk  = blockIdx.x;
    const int b    = blk / SPLIT3;
    const int s    = blk % SPLIT3;
    const int tid  = threadIdx.x;
    const int w    = tid >> 6, lane = tid & 63, lg = lane >> 4, lr = lane & 15;
    const float g  = gamma[0];

    short8 afr[4][2];
#pragma unroll
    for (int ct = 0; ct < 4; ++ct)
#pragma unroll
        for (int ks = 0; ks < 2; ++ks)
            afr[ct][ks] = *reinterpret_cast<const short8*>(
                att + (((size_t)b) << 12) + (ct * 16 + lr) * 64 + ks * 32 + lg * 8);

    float offv[4][4];
#pragma unroll
    for (int ct = 0; ct < 4; ++ct)
#pragma unroll
        for (int r = 0; r < 4; ++r)
            offv[ct][r] = offs[b * CC + ct * 16 + lg * 4 + r];

    const int colblock = s * (NN / SPLIT3);
    const int GROUPS = (NN / SPLIT3) / (4 * 64);   // 64-col groups per wave (=2)
    for (int itg = 0; itg < GROUPS; ++itg) {
        const int n0 = colblock + (w * GROUPS + itg) * 64;
        f32x4 acc[4][4];   // [phase][ct]
#pragma unroll
        for (int ph = 0; ph < 4; ++ph)
#pragma unroll
            for (int ct = 0; ct < 4; ++ct) acc[ph][ct] = (f32x4){0.f, 0.f, 0.f, 0.f};

#pragma unroll
        for (int ks = 0; ks < 2; ++ks) {
            short8 bfr[4];
            const int d0 = ks * 32 + lg * 8;
            if (CACHE) {
                const unsigned short* xp = xbf + ((size_t)(b * CC + d0)) * NN + n0 + lr * 4;
#pragma unroll
                for (int j = 0; j < 8; ++j) {
                    const short4v v = *reinterpret_cast<const short4v*>(xp + (size_t)j * NN);
                    bfr[0][j] = v.x; bfr[1][j] = v.y; bfr[2][j] = v.z; bfr[3][j] = v.w;
                }
            } else {
                const float* xp = x + ((size_t)(b * CC + d0)) * NN + n0 + lr * 4;
#pragma unroll
                for (int j = 0; j < 8; ++j) {
                    const float4 v = *reinterpret_cast<const float4*>(xp + (size_t)j * NN);
                    bfr[0][j] = f2bf(v.x);
                    bfr[1][j] = f2bf(v.y);
                    bfr[2][j] = f2bf(v.z);
                    bfr[3][j] = f2bf(v.w);
                }
            }
#pragma unroll
            for (int ct = 0; ct < 4; ++ct) {
#pragma unroll
                for (int ph = 0; ph < 4; ++ph)
                    acc[ph][ct] = mfma16(afr[ct][ks], bfr[ph], acc[ph][ct]);
            }
        }
#pragma unroll
        for (int ct = 0; ct < 4; ++ct) {
#pragma unroll
            for (int r = 0; r < 4; ++r) {
                const int c = ct * 16 + lg * 4 + r;
                const float o = offv[ct][r];
                f32x4 vs;
                vs[0] = g * (acc[0][ct][r] - o);
                vs[1] = g * (acc[1][ct][r] - o);
                vs[2] = g * (acc[2][ct][r] - o);
                vs[3] = g * (acc[3][ct][r] - o);
                __builtin_nontemporal_store(
                    vs, reinterpret_cast<f32x4*>(out + ((size_t)(b * CC + c)) * NN + n0 + lr * 4));
            }
        }
    }
}

extern "C" void kernel_launch(void* const* d_in, const int* in_sizes, int n_in,
                              void* d_out, int out_size, void* d_ws, size_t ws_size,
                              hipStream_t stream) {
    const float* x     = (const float*)d_in[0];
    const float* gamma = (const float*)d_in[1];
    float* out = (float*)d_out;

    // Large deterministic partials live at the FRONT of d_out (fully overwritten
    // by k3 afterwards). Small tables + bf16 x-cache live in d_ws.
    float* partialG = out;                                   // 8*64*4096 floats (8.4 MB)
    float* partialS = out + (size_t)BB * SPLIT1 * 4096;      // 8*64*64 floats
    float* Gsum     = partialS + BB * SPLIT1 * CC;           // 8*4096 floats
    float* offs     = (float*)d_ws;                          // 512 floats
    unsigned short* att = (unsigned short*)((char*)d_ws + 4096);  // 8*4096 bf16
    unsigned short* xbf = (unsigned short*)((char*)d_ws + (1 << 20));

    const size_t need = (size_t)(1 << 20) + (size_t)BB * CC * NN * 2;  // ~68.2 MB
    const bool cache = ws_size >= need;

    if (cache) {
        k1_gram<true><<<BB * SPLIT1, 256, 0, stream>>>(x, partialG, partialS, xbf);
        k2a_reduceG<<<(BB * 4096) / 256, 256, 0, stream>>>(partialG, Gsum);
        k2b_softmax<<<BB, 256, 0, stream>>>(partialS, Gsum, att, offs);
        k3_apply<true><<<BB * SPLIT3, 256, 0, stream>>>(x, xbf, att, offs, gamma, out);
    } else {
        k1_gram<false><<<BB * SPLIT1, 256, 0, stream>>>(x, partialG, partialS, xbf);
        k2a_reduceG<<<(BB * 4096) / 256, 256, 0, stream>>>(partialG, Gsum);
        k2b_softmax<<<BB, 256, 0, stream>>>(partialS, Gsum, att, offs);
        k3_apply<false><<<BB * SPLIT3, 256, 0, stream>>>(x, xbf, att, offs, gamma, out);
    }
}

// Round 8
// 86.495 us; speedup vs baseline: 1.0140x; 1.0140x over previous
//
#include <hip/hip_runtime.h>
#include <hip/hip_bf16.h>

typedef __attribute__((ext_vector_type(8))) short short8;
typedef __attribute__((ext_vector_type(4))) short short4v;
typedef __attribute__((ext_vector_type(4))) float f32x4;
typedef __attribute__((ext_vector_type(8))) __bf16 bf16x8;

#define BB 8
#define CC 64
#define NN 65536        // H*W = 256*256
#define SPLIT1 64       // k1 blocks per batch (512 total = 2 blocks/CU)
#define COLS1 (NN / SPLIT1)   // 1024 cols per k1 block
#define TILE_C 64             // fp32 tile cols: 64 x 64 x 4B = 16 KB per buffer
#define NT1 (COLS1 / TILE_C)  // 16 tiles per block
#define SPLIT3 128      // k3 blocks per batch

__device__ inline short f2bf(float f) {
    __hip_bfloat16 h = __float2bfloat16(f);
    return __builtin_bit_cast(short, h);
}

// --- MFMA wrapper: tolerate either short8 or bf16x8 builtin signature ---
template <typename V>
__device__ inline auto mfma_bf16_impl(V a, V b, f32x4 c, int)
    -> decltype(__builtin_amdgcn_mfma_f32_16x16x32_bf16(a, b, c, 0, 0, 0)) {
    return __builtin_amdgcn_mfma_f32_16x16x32_bf16(a, b, c, 0, 0, 0);
}
template <typename V>
__device__ inline f32x4 mfma_bf16_impl(V a, V b, f32x4 c, long) {
    bf16x8 a2 = __builtin_bit_cast(bf16x8, a);
    bf16x8 b2 = __builtin_bit_cast(bf16x8, b);
    return __builtin_amdgcn_mfma_f32_16x16x32_bf16(a2, b2, c, 0, 0, 0);
}
__device__ inline f32x4 mfma16(short8 a, short8 b, f32x4 c) {
    return mfma_bf16_impl(a, b, c, 0);
}

// ---- async global->LDS staging of one 64x64 fp32 tile (16 KB) ---------------
// LDS dest LINEAR (HW requirement: uniform base + lane*16). XOR swizzle
// ((row&15)<<4 on the in-row byte) applied to the GLOBAL source address
// (rule #21: pre-swizzled source + swizzled read = same involution).
__device__ inline void stage_tile(const float* __restrict__ xb, int colbase,
                                  float* buf, int tid) {
    const int slot  = tid & 15;          // 16-B slot within the 256-B row
    const int rg    = tid >> 4;          // row within each 16-row group
    const int gbyte = (slot ^ rg) << 4;  // pre-swizzled source byte
#pragma unroll
    for (int i = 0; i < 4; ++i) {
        const int row = i * 16 + rg;     // 0..63
        const float* gp = xb + (size_t)row * NN + colbase + (gbyte >> 2);
        float* lp = buf + i * 1024 + tid * 4;   // linear LDS dest
        __builtin_amdgcn_global_load_lds(
            (const __attribute__((address_space(1))) void*)gp,
            (__attribute__((address_space(3))) void*)lp, 16, 0, 0);
    }
}

// read 8 consecutive fp32 tile elements (row, cols c0..c0+7) through the swizzle
__device__ inline void lds_read8(const float* buf, int row, int c0, float* v) {
    const char* rb = (const char*)(buf + row * TILE_C);
    const int swz = (row & 15) << 4;
    const f32x4 u0 = *reinterpret_cast<const f32x4*>(rb + ((c0 * 4) ^ swz));
    const f32x4 u1 = *reinterpret_cast<const f32x4*>(rb + (((c0 * 4) + 16) ^ swz));
    v[0] = u0[0]; v[1] = u0[1]; v[2] = u0[2]; v[3] = u0[3];
    v[4] = u1[0]; v[5] = u1[1]; v[6] = u1[2]; v[7] = u1[3];
}

__device__ inline short8 cvt8(const float* v) {
    short8 r;
#pragma unroll
    for (int j = 0; j < 8; ++j) r[j] = f2bf(v[j]);
    return r;
}

// ------- Kernel 1: partial Gram (bf16 MFMA) + channel sums -------------------
// Depth-3 async pipeline with COUNTED vmcnt (T3/T4): never drain the
// global_load_lds queue at a barrier (the __syncthreads vmcnt(0) drain was
// the m97-style stall). 4 LDS buffers x 16 KB = 64 KB -> 2 blocks/CU.
__global__ __launch_bounds__(256) void k1_gram(const float* __restrict__ x,
                                               float* __restrict__ partialG,
                                               float* __restrict__ partialS) {
    __shared__ float lbuf[4][CC * TILE_C];
    const int blk  = blockIdx.x;
    const int b    = blk / SPLIT1;
    const int s    = blk % SPLIT1;
    const int tid  = threadIdx.x;
    const int w    = tid >> 6, lane = tid & 63, lg = lane >> 4, lr = lane & 15;
    const float* xb = x + (size_t)b * CC * NN;
    const int colbase0 = s * COLS1;

    f32x4 acc[4];
#pragma unroll
    for (int dt = 0; dt < 4; ++dt) acc[dt] = (f32x4){0.f, 0.f, 0.f, 0.f};
    float asum = 0.f;

    stage_tile(xb, colbase0 + 0 * TILE_C, lbuf[0], tid);
    stage_tile(xb, colbase0 + 1 * TILE_C, lbuf[1], tid);
    stage_tile(xb, colbase0 + 2 * TILE_C, lbuf[2], tid);

    for (int t = 0; t < NT1; ++t) {
        // tile t ready when only {t+1, t+2}'s loads (4 each) may be pending.
        if (t + 2 < NT1) {
            asm volatile("s_waitcnt vmcnt(8) lgkmcnt(0)" ::: "memory");
        } else if (t + 1 < NT1) {
            asm volatile("s_waitcnt vmcnt(4) lgkmcnt(0)" ::: "memory");
        } else {
            asm volatile("s_waitcnt vmcnt(0) lgkmcnt(0)" ::: "memory");
        }
        __builtin_amdgcn_s_barrier();
        // stage t+3 into buf[(t+3)&3] (= buf[(t-1)&3], whose readers all
        // finished before this barrier -- lgkmcnt(0) above enforces it).
        if (t + 3 < NT1)
            stage_tile(xb, colbase0 + (t + 3) * TILE_C, lbuf[(t + 3) & 3], tid);

        const float* buf = lbuf[t & 3];
#pragma unroll
        for (int kk = 0; kk < TILE_C / 32; ++kk) {
            const int c0 = kk * 32 + lg * 8;
            float av[8];
            lds_read8(buf, w * 16 + lr, c0, av);
#pragma unroll
            for (int j = 0; j < 8; ++j) asum += av[j];
            const short8 af = cvt8(av);
#pragma unroll
            for (int dt = 0; dt < 4; ++dt) {
                short8 bf;
                if (dt == w) {           // wave-uniform: B-row == A-row, reuse
                    bf = af;
                } else {
                    float bv[8];
                    lds_read8(buf, dt * 16 + lr, c0, bv);
                    bf = cvt8(bv);
                }
                acc[dt] = mfma16(af, bf, acc[dt]);
            }
        }
    }
    // ---- write partial Gram (C/D map: col=lane&15, row=(lane>>4)*4+reg) ----
#pragma unroll
    for (int dt = 0; dt < 4; ++dt) {
#pragma unroll
        for (int r = 0; r < 4; ++r) {
            const int c = w * 16 + lg * 4 + r;
            const int d = dt * 16 + lr;
            partialG[(size_t)blk * 4096 + c * 64 + d] = acc[dt][r];
        }
    }
    // ---- channel sums: reduce the lg quarters of each row ----
    float v = asum;
    v += __shfl_xor(v, 16);
    v += __shfl_xor(v, 32);
    if (lg == 0) partialS[blk * CC + w * 16 + lr] = v;
}

// ---------------- Kernel 2a: reduce partial Gram over splits ----------------
__global__ __launch_bounds__(256) void k2a_reduceG(const float* __restrict__ partialG,
                                                   float* __restrict__ Gsum) {
    const int gid = blockIdx.x * 256 + threadIdx.x;   // 0..32767
    const int b = gid >> 12;
    const int e = gid & 4095;
    float s = 0.f;
    for (int sp = 0; sp < SPLIT1; ++sp)
        s += partialG[(((size_t)(b * SPLIT1 + sp)) << 12) + e];
    Gsum[gid] = s;
}

// ------- Kernel 2b: means, energy, softmax -> att(bf16) + offsets -----------
__global__ __launch_bounds__(256) void k2b_softmax(const float* __restrict__ partialS,
                                                   const float* __restrict__ Gsum,
                                                   unsigned short* __restrict__ att,
                                                   float* __restrict__ offs) {
    __shared__ float mu[CC];
    __shared__ float ener[CC * CC];
    const int b = blockIdx.x;
    const int tid = threadIdx.x;
    if (tid < CC) {
        float s = 0.f;
        for (int sp = 0; sp < SPLIT1; ++sp) s += partialS[(b * SPLIT1 + sp) * CC + tid];
        mu[tid] = s * (1.f / NN);
    }
    __syncthreads();
    const float inv_n = 1.f / NN;
#pragma unroll
    for (int k = 0; k < 16; ++k) {
        const int e = tid + k * 256;
        const int c = e >> 6, d = e & 63;
        ener[e] = Gsum[(b << 12) + e] * inv_n - mu[c] * mu[d];
    }
    __syncthreads();
    const int w = tid >> 6, lane = tid & 63;
    for (int i = 0; i < 16; ++i) {
        const int c = w * 16 + i;
        const float v = ener[c * 64 + lane];
        float m = v;
        for (int off = 32; off > 0; off >>= 1) m = fmaxf(m, __shfl_xor(m, off));
        const float ev = __expf(v - m);
        float sum = ev;
        for (int off = 32; off > 0; off >>= 1) sum += __shfl_xor(sum, off);
        const float a = ev / sum;
        att[(b << 12) + c * 64 + lane] = (unsigned short)f2bf(a);
        float o = a * mu[lane];
        for (int off = 32; off > 0; off >>= 1) o += __shfl_xor(o, off);
        if (lane == 0) offs[b * CC + c] = o;
    }
}

// ---------------- Kernel 3: out = gamma * (A @ x - offset) ------------------
// Non-temporal stores keep x resident in Infinity Cache (134 MB < 256 MB L3).
__global__ __launch_bounds__(256) void k3_apply(const float* __restrict__ x,
                                                const unsigned short* __restrict__ att,
                                                const float* __restrict__ offs,
                                                const float* __restrict__ gamma,
                                                float* __restrict__ out) {
    const int blk  = blockIdx.x;
    const int b    = blk / SPLIT3;
    const int s    = blk % SPLIT3;
    const int tid  = threadIdx.x;
    const int w    = tid >> 6, lane = tid & 63, lg = lane >> 4, lr = lane & 15;
    const float g  = gamma[0];

    short8 afr[4][2];
#pragma unroll
    for (int ct = 0; ct < 4; ++ct)
#pragma unroll
        for (int ks = 0; ks < 2; ++ks)
            afr[ct][ks] = *reinterpret_cast<const short8*>(
                att + (((size_t)b) << 12) + (ct * 16 + lr) * 64 + ks * 32 + lg * 8);

    float offv[4][4];
#pragma unroll
    for (int ct = 0; ct < 4; ++ct)
#pragma unroll
        for (int r = 0; r < 4; ++r)
            offv[ct][r] = offs[b * CC + ct * 16 + lg * 4 + r];

    const int colblock = s * (NN / SPLIT3);
    const int GROUPS = (NN / SPLIT3) / (4 * 64);   // 64-col groups per wave (=2)
    for (int itg = 0; itg < GROUPS; ++itg) {
        const int n0 = colblock + (w * GROUPS + itg) * 64;
        f32x4 acc[4][4];   // [phase][ct]
#pragma unroll
        for (int ph = 0; ph < 4; ++ph)
#pragma unroll
            for (int ct = 0; ct < 4; ++ct) acc[ph][ct] = (f32x4){0.f, 0.f, 0.f, 0.f};

#pragma unroll
        for (int ks = 0; ks < 2; ++ks) {
            short8 bfr[4];
            const int d0 = ks * 32 + lg * 8;
            const float* xp = x + ((size_t)(b * CC + d0)) * NN + n0 + lr * 4;
#pragma unroll
            for (int j = 0; j < 8; ++j) {
                const float4 v = *reinterpret_cast<const float4*>(xp + (size_t)j * NN);
                bfr[0][j] = f2bf(v.x);
                bfr[1][j] = f2bf(v.y);
                bfr[2][j] = f2bf(v.z);
                bfr[3][j] = f2bf(v.w);
            }
#pragma unroll
            for (int ct = 0; ct < 4; ++ct) {
#pragma unroll
                for (int ph = 0; ph < 4; ++ph)
                    acc[ph][ct] = mfma16(afr[ct][ks], bfr[ph], acc[ph][ct]);
            }
        }
#pragma unroll
        for (int ct = 0; ct < 4; ++ct) {
#pragma unroll
            for (int r = 0; r < 4; ++r) {
                const int c = ct * 16 + lg * 4 + r;
                const float o = offv[ct][r];
                f32x4 vs;
                vs[0] = g * (acc[0][ct][r] - o);
                vs[1] = g * (acc[1][ct][r] - o);
                vs[2] = g * (acc[2][ct][r] - o);
                vs[3] = g * (acc[3][ct][r] - o);
                __builtin_nontemporal_store(
                    vs, reinterpret_cast<f32x4*>(out + ((size_t)(b * CC + c)) * NN + n0 + lr * 4));
            }
        }
    }
}

extern "C" void kernel_launch(void* const* d_in, const int* in_sizes, int n_in,
                              void* d_out, int out_size, void* d_ws, size_t ws_size,
                              hipStream_t stream) {
    const float* x     = (const float*)d_in[0];
    const float* gamma = (const float*)d_in[1];
    float* out = (float*)d_out;

    // Large deterministic partials live at the FRONT of d_out (fully overwritten
    // by k3 afterwards). Only the small att/offs tables use d_ws.
    float* partialG = out;                                   // 8*64*4096 floats (8.4 MB)
    float* partialS = out + (size_t)BB * SPLIT1 * 4096;      // 8*64*64 floats
    float* Gsum     = partialS + BB * SPLIT1 * CC;           // 8*4096 floats
    float* offs     = (float*)d_ws;                          // 512 floats
    unsigned short* att = (unsigned short*)((char*)d_ws + 4096);  // 8*4096 bf16

    k1_gram<<<BB * SPLIT1, 256, 0, stream>>>(x, partialG, partialS);
    k2a_reduceG<<<(BB * 4096) / 256, 256, 0, stream>>>(partialG, Gsum);
    k2b_softmax<<<BB, 256, 0, stream>>>(partialS, Gsum, att, offs);
    k3_apply<<<BB * SPLIT3, 256, 0, stream>>>(x, att, offs, gamma, out);
}